// Round 9
// baseline (1261.658 us; speedup 1.0000x reference)
//
#include <hip/hip_runtime.h>
#include <hip/hip_bf16.h>

#define TT    128
#define BATCH 1024
#define INDIM 512
#define HIDD  1024
#define NCLS  10

typedef __bf16 bf16x8 __attribute__((ext_vector_type(8)));
typedef float  f32x4  __attribute__((ext_vector_type(4)));
typedef unsigned short u16x8 __attribute__((ext_vector_type(8)));

__device__ __forceinline__ unsigned short bf16b(float f) {
    __hip_bfloat16 h = __float2bfloat16(f);
    return __builtin_bit_cast(unsigned short, h);
}

__device__ __forceinline__ float tanh_fast(float x) {
    float e = __expf(2.0f * x);
    return 1.0f - 2.0f * __builtin_amdgcn_rcpf(e + 1.0f);
}

#define WAITV(n) asm volatile("s_waitcnt vmcnt(" #n ")" ::: "memory")
#define WAITL()  asm volatile("s_waitcnt lgkmcnt(0)" ::: "memory")
#define BAR()    asm volatile("s_barrier" ::: "memory")

// ---------------------------------------------------------------------------
// Prep: W -> transposed bf16 hi/lo pairs (unchanged, verified R1-R8).
// ---------------------------------------------------------------------------
__global__ __launch_bounds__(256) void prep_kernel(
    const float* __restrict__ Whh, const float* __restrict__ Wxh,
    __hip_bfloat16* __restrict__ WhhT_hi, __hip_bfloat16* __restrict__ WhhT_lo,
    __hip_bfloat16* __restrict__ WxhT_hi, __hip_bfloat16* __restrict__ WxhT_lo)
{
    __shared__ float tl[64][68];
    int bid = blockIdx.x, tid = threadIdx.x;
    const float* src; int N, k0, n0, dstride;
    __hip_bfloat16 *dhi, *dlo;
    if (bid < 256) { src = Whh; N = 1024; k0 = (bid >> 4) << 6; n0 = (bid & 15) << 6;
                     dhi = WhhT_hi; dlo = WhhT_lo; dstride = 1024; }
    else { int b = bid - 256; src = Wxh; N = 1024; k0 = (b >> 4) << 6; n0 = (b & 15) << 6;
           dhi = WxhT_hi; dlo = WxhT_lo; dstride = 512; }

    int r = tid >> 2, c0 = (tid & 3) << 4;
    const float* s = src + (size_t)(k0 + r) * N + n0 + c0;
#pragma unroll
    for (int j = 0; j < 4; ++j)
        *(float4*)&tl[r][c0 + j * 4] = *(const float4*)(s + j * 4);
    __syncthreads();

    int rn = tid >> 2, ck0 = (tid & 3) << 4;
    u16x8 hi0, hi1, lo0, lo1;
#pragma unroll
    for (int j = 0; j < 16; ++j) {
        float w = tl[ck0 + j][rn];
        unsigned short hb = bf16b(w);
        float hf = __bfloat162float(__builtin_bit_cast(__hip_bfloat16, hb));
        unsigned short lb = bf16b(w - hf);
        if (j < 8) { hi0[j] = hb; lo0[j] = lb; }
        else       { hi1[j - 8] = hb; lo1[j - 8] = lb; }
    }
    size_t o = (size_t)(n0 + rn) * dstride + k0 + ck0;
    *(u16x8*)(void*)(dhi + o)     = hi0;
    *(u16x8*)(void*)(dhi + o + 8) = hi1;
    *(u16x8*)(void*)(dlo + o)     = lo0;
    *(u16x8*)(void*)(dlo + o + 8) = lo1;
}

// ---------------------------------------------------------------------------
__global__ __launch_bounds__(256) void convx_all_kernel(
    const float* __restrict__ x, __hip_bfloat16* __restrict__ xs)
{
    size_t gid = (size_t)blockIdx.x * 256 + threadIdx.x;
    int i  = (int)(gid & 63) << 3;
    size_t bt = gid >> 6;
    int t = (int)(bt & 127);
    int b = (int)(bt >> 7);
    const float* s = x + ((size_t)b * TT + t) * INDIM + i;
    float4 a0 = *(const float4*)s, a1 = *(const float4*)(s + 4);
    u16x8 o;
    o[0]=bf16b(a0.x); o[1]=bf16b(a0.y); o[2]=bf16b(a0.z); o[3]=bf16b(a0.w);
    o[4]=bf16b(a1.x); o[5]=bf16b(a1.y); o[6]=bf16b(a1.z); o[7]=bf16b(a1.w);
    *(u16x8*)(void*)(xs + ((size_t)t * BATCH + b) * INDIM + i) = o;
}

__global__ __launch_bounds__(256) void zero_kernel(
    __hip_bfloat16* __restrict__ h, unsigned* __restrict__ bar)
{
    if (blockIdx.x < 512) {
        size_t i = ((size_t)blockIdx.x * 256 + threadIdx.x) << 3;
        u16x8 z = {0,0,0,0,0,0,0,0};
        *(u16x8*)(void*)(h + i) = z;
    } else {
        uint4 z = {0,0,0,0};
#pragma unroll
        for (int k = 0; k < 8; ++k)
            ((uint4*)bar)[k * 256 + threadIdx.x] = z;
    }
}

// ---------------------------------------------------------------------------
// Persistent RNN, R9: K-SPLIT waves. Wave w owns K-rows [w*384,+384) =
// x-chunks {2w..} (K=128 as 2x64) + h-chunks {4 of K=64}, for ALL 64 block
// cols. B regs/wave: Bh[64]+Bx[32] frags = 384 regs (AGPR). acc = full 64x64
// f32 partial (16 f32x4). Per-wave private LDS: 4 x 8KB bufs (rotating x/h
// roles by step parity). NO barriers in compute; per-wave upfront poll of
// its 4 producer blocks; cross-wave reduction via LDS once per step (2 BARs).
// ---------------------------------------------------------------------------
#define FRAGA64(_b, m, ks) \
    (*(const bf16x8*)((_b) + ((((m)<<4)+ar) << 7) + (((((ks)<<2)+kg) ^ (ar & 7)) << 4)))

// Stage one 64-row x 64-K bf16 chunk (8KB) by ONE wave: 8 global_load_lds.
#define STAGEW(basePtr, rs, bufptr, AUX) do {                                  \
    _Pragma("unroll")                                                          \
    for (int _i = 0; _i < 8; ++_i) {                                           \
        const void* _g = (const void*)((basePtr) + (size_t)((_i<<3) + l3) * (rs) + se); \
        void* _l = (void*)((bufptr) + (_i << 10));                             \
        __builtin_amdgcn_global_load_lds(                                      \
            (const __attribute__((address_space(1))) void*)_g,                 \
            (__attribute__((address_space(3))) void*)_l, 16, 0, AUX);          \
    } } while (0)

// One K=64 chunk: 8 A-frag reads, 64 MFMAs into acc[4][4] (16 chains).
#define DO_CHUNK64(B_ARR, qb, bufptr) do {                                     \
    _Pragma("unroll")                                                          \
    for (int _ks = 0; _ks < 2; ++_ks) {                                        \
        bf16x8 a0 = FRAGA64(bufptr, 0, _ks), a1 = FRAGA64(bufptr, 1, _ks);     \
        bf16x8 a2 = FRAGA64(bufptr, 2, _ks), a3 = FRAGA64(bufptr, 3, _ks);     \
        _Pragma("unroll")                                                      \
        for (int _cg = 0; _cg < 4; ++_cg) {                                    \
            bf16x8 bh = B_ARR[((qb)+_ks)*8 + _cg*2 + 0];                       \
            acc[0][_cg] = __builtin_amdgcn_mfma_f32_16x16x32_bf16(a0, bh, acc[0][_cg], 0,0,0); \
            acc[1][_cg] = __builtin_amdgcn_mfma_f32_16x16x32_bf16(a1, bh, acc[1][_cg], 0,0,0); \
            acc[2][_cg] = __builtin_amdgcn_mfma_f32_16x16x32_bf16(a2, bh, acc[2][_cg], 0,0,0); \
            acc[3][_cg] = __builtin_amdgcn_mfma_f32_16x16x32_bf16(a3, bh, acc[3][_cg], 0,0,0); \
        }                                                                      \
        _Pragma("unroll")                                                      \
        for (int _cg = 0; _cg < 4; ++_cg) {                                    \
            bf16x8 bl = B_ARR[((qb)+_ks)*8 + _cg*2 + 1];                       \
            acc[0][_cg] = __builtin_amdgcn_mfma_f32_16x16x32_bf16(a0, bl, acc[0][_cg], 0,0,0); \
            acc[1][_cg] = __builtin_amdgcn_mfma_f32_16x16x32_bf16(a1, bl, acc[1][_cg], 0,0,0); \
            acc[2][_cg] = __builtin_amdgcn_mfma_f32_16x16x32_bf16(a2, bl, acc[2][_cg], 0,0,0); \
            acc[3][_cg] = __builtin_amdgcn_mfma_f32_16x16x32_bf16(a3, bl, acc[3][_cg], 0,0,0); \
        }                                                                      \
    } } while (0)

__global__ __launch_bounds__(256, 1) void rnn_kernel(
    __hip_bfloat16* __restrict__ h0, __hip_bfloat16* __restrict__ h1,
    const __hip_bfloat16* __restrict__ xs,
    const __hip_bfloat16* __restrict__ WhhT_hi, const __hip_bfloat16* __restrict__ WhhT_lo,
    const __hip_bfloat16* __restrict__ WxhT_hi, const __hip_bfloat16* __restrict__ WxhT_lo,
    const float* __restrict__ b_xh, const float* __restrict__ b_hh,
    unsigned* __restrict__ bar)
{
    __shared__ char smem[131072];                // 4 waves x 4 x 8KB bufs
    int tid = threadIdx.x, bid = blockIdx.x;
    int by = (bid & 7) | (((bid >> 3) & 1) << 3);   // XCD-local groups (R6)
    int bx = bid >> 4;
    int lane = tid & 63, w = tid >> 6;
    int ar = lane & 15, kg = lane >> 4;
    int l3 = lane >> 3;
    int se = ((lane & 7) ^ l3) << 3;             // pre-swizzled source elem off
    int bx64 = bx << 6, by64 = by << 6;
    char* wb = smem + (w << 15);                 // this wave's 32KB

    // ---- weights: wave's K-slice x all 64 cols. Bh 64 + Bx 32 frags ----
    bf16x8 Bh[64], Bx[32];
    float bias[4];
#pragma unroll
    for (int cg = 0; cg < 4; ++cg) {
        int col = bx64 + (cg << 4) + ar;
        bias[cg] = b_xh[col] + b_hh[col];
#pragma unroll
        for (int kc = 0; kc < 8; ++kc) {
            int k = (w << 8) + (kc << 5) + (kg << 3);
            Bh[kc*8 + cg*2 + 0] = *(const bf16x8*)(WhhT_hi + (size_t)col * HIDD + k);
            Bh[kc*8 + cg*2 + 1] = *(const bf16x8*)(WhhT_lo + (size_t)col * HIDD + k);
        }
#pragma unroll
        for (int kc = 0; kc < 4; ++kc) {
            int k = (w << 7) + (kc << 5) + (kg << 3);
            Bx[kc*8 + cg*2 + 0] = *(const bf16x8*)(WxhT_hi + (size_t)col * INDIM + k);
            Bx[kc*8 + cg*2 + 1] = *(const bf16x8*)(WxhT_lo + (size_t)col * INDIM + k);
        }
    }

    unsigned* grpflags = bar + (by << 9);
    unsigned* myflag   = grpflags + (bx << 5);

    // Prologue: stage x(0) chunks (t=0 -> xsel=2: bufs b2,b3).
    {
        const __hip_bfloat16* xA0 = xs + (size_t)by64 * INDIM + (w << 7);
        STAGEW(xA0,      INDIM, wb + (2 << 13), 0);
        STAGEW(xA0 + 64, INDIM, wb + (3 << 13), 0);
    }

    for (int t = 0; t < TT; ++t) {
        const __hip_bfloat16* hA = (t & 1) ? h1 : h0;
        __hip_bfloat16*       hB = (t & 1) ? h0 : h1;
        const __hip_bfloat16* hR = hA + (size_t)by64 * HIDD + (w << 8);
        const __hip_bfloat16* xN = xs + (size_t)(t + 1) * (BATCH * INDIM)
                                      + (size_t)by64 * INDIM + (w << 7);
        int nl = (t < TT - 1);
        int xsel = (t & 1) ? 0 : 2;              // x bufs this step
        char* bX0 = wb + (xsel << 13);
        char* bX1 = bX0 + 8192;
        char* bH0 = wb + ((xsel ^ 2) << 13);     // other pair
        char* bH1 = bH0 + 8192;

        f32x4 acc[4][4];
#pragma unroll
        for (int m = 0; m < 4; ++m)
#pragma unroll
            for (int cg = 0; cg < 4; ++cg) acc[m][cg] = (f32x4){0,0,0,0};

        // ===== x compute (wave-private, no barriers) =======================
        WAITV(8);  DO_CHUNK64(Bx, 0, bX0);
        WAITV(0);  DO_CHUNK64(Bx, 2, bX1);

        // ===== poll this wave's 4 producer blocks (vm queue empty here) ====
        {
            unsigned tgt = (unsigned)t;
            const unsigned* fp = grpflags + (((w << 2) + (lane & 3)) << 5);
            for (;;) {
                unsigned v = __hip_atomic_load(fp, __ATOMIC_RELAXED,
                                               __HIP_MEMORY_SCOPE_AGENT);
                if (__all(v >= tgt)) break;
                __builtin_amdgcn_s_sleep(1);
            }
        }

        // ===== h phase: 4 chunks, private dbuf, counted vmcnt ==============
        STAGEW(hR,       HIDD, bH0, 1);          // H0
        STAGEW(hR +  64, HIDD, bH1, 1);          // H1
        STAGEW(hR + 128, HIDD, bX0, 1);          // H2 (x bufs now free)
        STAGEW(hR + 192, HIDD, bX1, 1);          // H3
        WAITV(24); DO_CHUNK64(Bh, 0, bH0);
        WAITV(16); DO_CHUNK64(Bh, 2, bH1);
        if (nl) {                                // prefetch x(t+1) -> bH0,bH1
            STAGEW(xN,      INDIM, bH0, 0);
            STAGEW(xN + 64, INDIM, bH1, 0);
            WAITV(24); DO_CHUNK64(Bh, 4, bX0);
            WAITV(16); DO_CHUNK64(Bh, 6, bX1);
        } else {
            WAITV(8);  DO_CHUNK64(Bh, 4, bX0);
            WAITV(0);  DO_CHUNK64(Bh, 6, bX1);
        }

        // ===== cross-wave reduction (partials in bX0..bX1 = 16KB) ==========
        {
            char* pr = wb + (xsel << 13);
#pragma unroll
            for (int m = 0; m < 4; ++m)
#pragma unroll
                for (int cg = 0; cg < 4; ++cg)
                    *(f32x4*)(pr + (((m << 2) + cg) << 10) + (lane << 4)) = acc[m][cg];
        }
        WAITL(); BAR();                          // partials visible

        f32x4 s0 = {0,0,0,0}, s1 = {0,0,0,0}, s2 = {0,0,0,0}, s3 = {0,0,0,0};
#pragma unroll
        for (int v = 0; v < 4; ++v) {
            const char* prv = smem + (v << 15) + (xsel << 13) + ((w << 2) << 10) + (lane << 4);
            s0 += *(const f32x4*)(prv);
            s1 += *(const f32x4*)(prv + 1024);
            s2 += *(const f32x4*)(prv + 2048);
            s3 += *(const f32x4*)(prv + 3072);
        }

        // ===== epilogue: bias + tanh + store rows [by64+16w, +16) ==========
#pragma unroll
        for (int cg = 0; cg < 4; ++cg) {
            f32x4 sv = (cg == 0) ? s0 : (cg == 1) ? s1 : (cg == 2) ? s2 : s3;
            int col = bx64 + (cg << 4) + ar;
            float bs = bias[cg];
#pragma unroll
            for (int j = 0; j < 4; ++j) {
                int row = by64 + (w << 4) + (kg << 2) + j;
                hB[(size_t)row * HIDD + col] = __float2bfloat16(tanh_fast(sv[j] + bs));
            }
        }
        WAITV(0);                                // h stores (+x') drained
        BAR();                                   // all waves done: bufs+flags safe
        if (nl && tid == 0)
            __hip_atomic_store(myflag, (unsigned)(t + 1), __ATOMIC_RELAXED,
                               __HIP_MEMORY_SCOPE_AGENT);
    }
}

// ---------------------------------------------------------------------------
__global__ __launch_bounds__(64) void out_kernel(
    const __hip_bfloat16* __restrict__ h, const float* __restrict__ Why,
    const float* __restrict__ b_y, float* __restrict__ out)
{
    int b = blockIdx.x, lane = threadIdx.x;
    float acc[NCLS];
#pragma unroll
    for (int c = 0; c < NCLS; ++c) acc[c] = 0.f;
    for (int kk = 0; kk < 16; ++kk) {
        int k = (kk << 6) + lane;
        float hv = __bfloat162float(h[(size_t)b * HIDD + k]);
#pragma unroll
        for (int c = 0; c < NCLS; ++c) acc[c] += hv * Why[(size_t)k * NCLS + c];
    }
#pragma unroll
    for (int c = 0; c < NCLS; ++c) {
        float v = acc[c];
#pragma unroll
        for (int off = 32; off > 0; off >>= 1) v += __shfl_down(v, off);
        if (lane == 0) out[(size_t)b * NCLS + c] = v + b_y[c];
    }
}

// ---------------------------------------------------------------------------
extern "C" void kernel_launch(void* const* d_in, const int* in_sizes, int n_in,
                              void* d_out, int out_size, void* d_ws, size_t ws_size,
                              hipStream_t stream)
{
    const float* x    = (const float*)d_in[0];
    const float* Wxh  = (const float*)d_in[1];
    const float* b_xh = (const float*)d_in[2];
    const float* Whh  = (const float*)d_in[3];
    const float* b_hh = (const float*)d_in[4];
    const float* Why  = (const float*)d_in[5];
    const float* b_y  = (const float*)d_in[6];
    float* out = (float*)d_out;

    char* ws = (char*)d_ws;                       // 144 MB used
    __hip_bfloat16* WhhT_hi = (__hip_bfloat16*)(ws);
    __hip_bfloat16* WhhT_lo = (__hip_bfloat16*)(ws + (2u  << 20));
    __hip_bfloat16* WxhT_hi = (__hip_bfloat16*)(ws + (4u  << 20));
    __hip_bfloat16* WxhT_lo = (__hip_bfloat16*)(ws + (5u  << 20));
    __hip_bfloat16* h0      = (__hip_bfloat16*)(ws + (6u  << 20));
    __hip_bfloat16* h1      = (__hip_bfloat16*)(ws + (8u  << 20));
    unsigned*       bar     = (unsigned*)      (ws + (10u << 20));
    __hip_bfloat16* xs      = (__hip_bfloat16*)(ws + (16u << 20));  // 128 MB

    prep_kernel<<<384, 256, 0, stream>>>(Whh, Wxh, WhhT_hi, WhhT_lo, WxhT_hi, WxhT_lo);
    convx_all_kernel<<<32768, 256, 0, stream>>>(x, xs);
    zero_kernel<<<513, 256, 0, stream>>>(h0, bar);

    rnn_kernel<<<256, 256, 0, stream>>>(h0, h1, xs,
                                        WhhT_hi, WhhT_lo, WxhT_hi, WxhT_lo,
                                        b_xh, b_hh, bar);

    out_kernel<<<1024, 64, 0, stream>>>(h0, Why, b_y, out);  // final h is in h0
}